// Round 2
// baseline (273.616 us; speedup 1.0000x reference)
//
#include <hip/hip_runtime.h>
#include <stdint.h>

// Problem constants
#define BATCH 16384
#define INDIM 256
#define DDIM  128
#define NEXP  8
#define ROWS  32          // batch rows per block (mt=2 row-tiles of 16)

typedef __bf16 bfv8  __attribute__((ext_vector_type(8)));   // MFMA A/B frag: 8 bf16 = 4 VGPRs
typedef float  f32x4 __attribute__((ext_vector_type(4)));   // MFMA C/D frag

// ---------------------------------------------------------------------------
// Prep kernel: repack Wa/Wb/Ws (fp32 [8,256,128]) and Gcat (Ga16|Gb16|Gs24 pad
// to 64 rows) into bf16 MFMA B-fragment layout so the main kernel's B loads
// are contiguous 1KB-per-wave dwordx4.
//   W frag slot t = (((st*8+e)*8+kt)*8+nt)*64+lane ; elem j = W[i][d] with
//     i = kt*32 + (lane>>4)*8 + j,  d = nt*16 + (lane&15)
//   G frag slot t2 = (kt*4+nt)*64+lane ; row g = nt*16+(lane&15), col k likewise
// ---------------------------------------------------------------------------
__global__ void prep_kernel(const float* __restrict__ Wa, const float* __restrict__ Wb,
                            const float* __restrict__ Ws, const float* __restrict__ Ga,
                            const float* __restrict__ Gb, const float* __restrict__ Gs,
                            __bf16* __restrict__ wp, __bf16* __restrict__ gp) {
    int t = blockIdx.x * 256 + threadIdx.x;
    const int NW = 3 * 8 * 8 * 8 * 64;   // 98304 W-frag slots
    if (t < NW) {
        int lane = t & 63, nt = (t >> 6) & 7, kt = (t >> 9) & 7, e = (t >> 12) & 7, st = t >> 15;
        const float* W = (st == 0) ? Wa : (st == 1) ? Wb : Ws;
        int d  = nt * 16 + (lane & 15);
        int i0 = kt * 32 + (lane >> 4) * 8;
        __bf16* o = wp + (size_t)t * 8;
#pragma unroll
        for (int j = 0; j < 8; j++)
            o[j] = (__bf16)W[(size_t)(e * 256 + i0 + j) * 128 + d];
    } else if (t < NW + 2048) {
        int t2 = t - NW;
        int lane = t2 & 63, nt = (t2 >> 6) & 3, kt = t2 >> 8;
        int g  = nt * 16 + (lane & 15);
        int k0 = kt * 32 + (lane >> 4) * 8;
        __bf16* o = gp + (size_t)t2 * 8;
#pragma unroll
        for (int j = 0; j < 8; j++) {
            int k = k0 + j;
            float v = 0.f;
            if (g < 16)      v = Ga[g * 256 + k];
            else if (g < 32) v = Gb[(g - 16) * 256 + k];
            else if (g < 56) v = Gs[(g - 32) * 256 + k];
            o[j] = (__bf16)v;
        }
    }
}

// ---------------------------------------------------------------------------
// Main fused kernel. Grid 512 blocks (2/CU) x 256 threads (4 waves).
// Block owns 32 batch rows (mt=2). Wave w owns output cols [32w, 32w+32).
// Register audit (per lane): afr 2*8*4=64, o 3*2*2*4=48, bf 8*2*4=64,
// acc 2*2*4=16, misc ~25 => ~215 VGPRs, no spills at the 256 cap.
// __launch_bounds__(256,2): 2 waves/SIMD => cap 256 VGPRs, 2 blocks/CU.
// ---------------------------------------------------------------------------
__launch_bounds__(256, 2)
__global__ void ple_kernel(const float* __restrict__ xa, const float* __restrict__ xb,
                           const float* __restrict__ xs,
                           const float* __restrict__ ba, const float* __restrict__ bb,
                           const float* __restrict__ bs,
                           const __bf16* __restrict__ wp, const __bf16* __restrict__ gp,
                           float* __restrict__ out) {
    __shared__ float lgt[ROWS * 64];   // logits [row][gate]
    __shared__ float wT[64 * ROWS];    // softmax weights transposed [gate][row]

    const int tid  = threadIdx.x;
    const int w    = tid >> 6;       // wave id 0..3
    const int lane = tid & 63;
    const int quad = lane >> 4;      // 0..3
    const int l16  = lane & 15;
    const int r0   = blockIdx.x * ROWS;

    const float* xptr[3] = {xa, xb, xs};
    const float* bptr[3] = {ba, bb, bs};

    bfv8 afr[2][8];                  // A frags: 2 row-tiles x 8 k-tiles (64 VGPRs)

    // ---------------- Phase 1: gate logits via MFMA ----------------
    if (w < 3) {
        const float* x = xptr[w];
#pragma unroll
        for (int mt = 0; mt < 2; mt++) {
            const float* xr = x + (size_t)(r0 + mt * 16 + l16) * INDIM;
#pragma unroll
            for (int kt = 0; kt < 8; kt++) {
                f32x4 lo = *(const f32x4*)(xr + kt * 32 + quad * 8);
                f32x4 hi = *(const f32x4*)(xr + kt * 32 + quad * 8 + 4);
                bfv8 a;
                a[0] = (__bf16)lo[0]; a[1] = (__bf16)lo[1]; a[2] = (__bf16)lo[2]; a[3] = (__bf16)lo[3];
                a[4] = (__bf16)hi[0]; a[5] = (__bf16)hi[1]; a[6] = (__bf16)hi[2]; a[7] = (__bf16)hi[3];
                afr[mt][kt] = a;
            }
        }
        const int nt0 = (w == 2) ? 2 : w;    // wave0->Ga(nt0), wave1->Gb(nt1), wave2->Gs(nt2,3)
        const int nnt = (w == 2) ? 2 : 1;
        for (int ntl = 0; ntl < nnt; ntl++) {
            int nt = nt0 + ntl;
            f32x4 acc[2];
#pragma unroll
            for (int mt = 0; mt < 2; mt++) { f32x4 z = {0.f, 0.f, 0.f, 0.f}; acc[mt] = z; }
#pragma unroll
            for (int kt = 0; kt < 8; kt++) {
                bfv8 g = *(const bfv8*)(gp + ((size_t)(kt * 4 + nt) * 64 + lane) * 8);
#pragma unroll
                for (int mt = 0; mt < 2; mt++)
                    acc[mt] = __builtin_amdgcn_mfma_f32_16x16x32_bf16(afr[mt][kt], g, acc[mt], 0, 0, 0);
            }
#pragma unroll
            for (int mt = 0; mt < 2; mt++)
#pragma unroll
                for (int r = 0; r < 4; r++)
                    lgt[(mt * 16 + quad * 4 + r) * 64 + nt * 16 + l16] = acc[mt][r];
        }
    }
    __syncthreads();

    // ---------------- softmax per row, 3 gate groups; store transposed ----------------
    if (tid < ROWS) {
        const float* L = lgt + tid * 64;
#pragma unroll
        for (int gi = 0; gi < 3; gi++) {
            const int base = (gi == 0) ? 0 : (gi == 1 ? 16 : 32);
            const int cnt  = (gi == 2) ? 24 : 16;
            float m = -1e30f;
            for (int k = 0; k < cnt; k++) m = fmaxf(m, L[base + k]);
            float s = 0.f;
            for (int k = 0; k < cnt; k++) s += __expf(L[base + k] - m);
            float inv = 1.f / s;
            for (int k = 0; k < cnt; k++) wT[(base + k) * ROWS + tid] = __expf(L[base + k] - m) * inv;
        }
    }
    __syncthreads();

    // ---------------- Phase 2: experts + gated accumulation ----------------
    float o[3][2][2][4];             // [out][mt][ntl][reg] = 48 VGPRs
#pragma unroll
    for (int oi = 0; oi < 3; oi++)
#pragma unroll
        for (int mt = 0; mt < 2; mt++)
#pragma unroll
            for (int ntl = 0; ntl < 2; ntl++)
#pragma unroll
                for (int r = 0; r < 4; r++) o[oi][mt][ntl][r] = 0.f;

// fold expert tile (acc, already biased) into output oi with gate column gbase+e
#define FOLD(oi, gbase)                                                            \
    {                                                                              \
        _Pragma("unroll")                                                          \
        for (int mt = 0; mt < 2; mt++) {                                           \
            f32x4 wv = *(const f32x4*)(wT + (gbase + e) * ROWS + mt * 16 + quad * 4); \
            _Pragma("unroll")                                                      \
            for (int ntl = 0; ntl < 2; ntl++)                                      \
                _Pragma("unroll")                                                  \
                for (int r = 0; r < 4; r++)                                        \
                    o[oi][mt][ntl][r] += wv[r] * acc[mt][ntl][r];                  \
        }                                                                          \
    }

#pragma unroll
    for (int st = 0; st < 3; st++) {
        const float* x = xptr[st];
#pragma unroll
        for (int mt = 0; mt < 2; mt++) {
            const float* xr = x + (size_t)(r0 + mt * 16 + l16) * INDIM;
#pragma unroll
            for (int kt = 0; kt < 8; kt++) {
                f32x4 lo = *(const f32x4*)(xr + kt * 32 + quad * 8);
                f32x4 hi = *(const f32x4*)(xr + kt * 32 + quad * 8 + 4);
                bfv8 a;
                a[0] = (__bf16)lo[0]; a[1] = (__bf16)lo[1]; a[2] = (__bf16)lo[2]; a[3] = (__bf16)lo[3];
                a[4] = (__bf16)hi[0]; a[5] = (__bf16)hi[1]; a[6] = (__bf16)hi[2]; a[7] = (__bf16)hi[3];
                afr[mt][kt] = a;
            }
        }
        const float* bias = bptr[st];
#pragma unroll
        for (int e = 0; e < NEXP; e++) {
            // B frags for this expert, this wave's 2 n-tiles: 16x coalesced 1KB loads (L2)
            bfv8 bf[8][2];
#pragma unroll
            for (int kt = 0; kt < 8; kt++)
#pragma unroll
                for (int ntl = 0; ntl < 2; ntl++)
                    bf[kt][ntl] = *(const bfv8*)(wp +
                        ((size_t)(((st * 8 + e) * 8 + kt) * 8 + (2 * w + ntl)) * 64 + lane) * 8);

            f32x4 acc[2][2];
#pragma unroll
            for (int mt = 0; mt < 2; mt++)
#pragma unroll
                for (int ntl = 0; ntl < 2; ntl++) { f32x4 z = {0.f, 0.f, 0.f, 0.f}; acc[mt][ntl] = z; }

#pragma unroll
            for (int kt = 0; kt < 8; kt++)
#pragma unroll
                for (int ntl = 0; ntl < 2; ntl++)
#pragma unroll
                    for (int mt = 0; mt < 2; mt++)
                        acc[mt][ntl] = __builtin_amdgcn_mfma_f32_16x16x32_bf16(
                            afr[mt][kt], bf[kt][ntl], acc[mt][ntl], 0, 0, 0);

            // bias (per output column)
            float b0 = bias[e * 128 + w * 32 + l16];
            float b1 = bias[e * 128 + w * 32 + 16 + l16];
#pragma unroll
            for (int mt = 0; mt < 2; mt++)
#pragma unroll
                for (int r = 0; r < 4; r++) { acc[mt][0][r] += b0; acc[mt][1][r] += b1; }

            // gated fold. Gate table columns: a:0-15, b:16-31, s:32-55.
            // out_a = cat(ea,es): ea->g=e,   es->g=8+e
            // out_b = cat(eb,es): eb->g=16+e (local 0..7), es->g=24+e
            // out_s = cat(ea,eb,es): ea->32+e, eb->40+e, es->48+e
            if (st == 0)      { FOLD(0, 0);  FOLD(2, 32); }
            else if (st == 1) { FOLD(1, 16); FOLD(2, 40); }
            else              { FOLD(0, 8);  FOLD(1, 24); FOLD(2, 48); }
        }
    }
#undef FOLD

    // ---------------- epilogue: store 3 outputs ----------------
#pragma unroll
    for (int oi = 0; oi < 3; oi++) {
        float* ob = out + (size_t)oi * BATCH * DDIM;
#pragma unroll
        for (int mt = 0; mt < 2; mt++)
#pragma unroll
            for (int r = 0; r < 4; r++) {
                int row = r0 + mt * 16 + quad * 4 + r;
#pragma unroll
                for (int ntl = 0; ntl < 2; ntl++)
                    ob[(size_t)row * DDIM + w * 32 + ntl * 16 + l16] = o[oi][mt][ntl][r];
            }
    }
}

extern "C" void kernel_launch(void* const* d_in, const int* in_sizes, int n_in,
                              void* d_out, int out_size, void* d_ws, size_t ws_size,
                              hipStream_t stream) {
    const float* xa = (const float*)d_in[0];
    const float* xb = (const float*)d_in[1];
    const float* xs = (const float*)d_in[2];
    const float* Wa = (const float*)d_in[3];
    const float* ba = (const float*)d_in[4];
    const float* Wb = (const float*)d_in[5];
    const float* bb = (const float*)d_in[6];
    const float* Ws = (const float*)d_in[7];
    const float* bs = (const float*)d_in[8];
    const float* Ga = (const float*)d_in[9];
    const float* Gb = (const float*)d_in[10];
    const float* Gs = (const float*)d_in[11];

    __bf16* wp = (__bf16*)d_ws;            // 786432 bf16 = 1.5 MB packed expert weights
    __bf16* gp = wp + 3 * 8 * 8 * 8 * 64 * 8;  // 16384 bf16 packed gate matrix

    prep_kernel<<<392, 256, 0, stream>>>(Wa, Wb, Ws, Ga, Gb, Gs, wp, gp);
    ple_kernel<<<BATCH / ROWS, 256, 0, stream>>>(xa, xb, xs, ba, bb, bs, wp, gp, (float*)d_out);
}

// Round 3
// 174.604 us; speedup vs baseline: 1.5671x; 1.5671x over previous
//
#include <hip/hip_runtime.h>
#include <stdint.h>

// Problem constants
#define BATCH 16384
#define INDIM 256
#define DDIM  128
#define NEXP  8
#define ROWS  32          // batch rows per block (mt=2 row-tiles of 16)

typedef __bf16 bfv8  __attribute__((ext_vector_type(8)));   // MFMA A/B frag: 8 bf16 = 4 VGPRs
typedef float  f32x4 __attribute__((ext_vector_type(4)));   // MFMA C/D frag

// ---------------------------------------------------------------------------
// Prep kernel: repack Wa/Wb/Ws (fp32 [8,256,128]) and Gcat (Ga16|Gb16|Gs24 pad
// to 64 rows) into bf16 MFMA B-fragment layout so the main kernel's B loads
// are contiguous 1KB-per-wave dwordx4.
//   W frag slot t = (((st*8+e)*8+kt)*8+nt)*64+lane ; elem j = W[i][d] with
//     i = kt*32 + (lane>>4)*8 + j,  d = nt*16 + (lane&15)
//   G frag slot t2 = (kt*4+nt)*64+lane ; row g = nt*16+(lane&15), col k likewise
// ---------------------------------------------------------------------------
__global__ void prep_kernel(const float* __restrict__ Wa, const float* __restrict__ Wb,
                            const float* __restrict__ Ws, const float* __restrict__ Ga,
                            const float* __restrict__ Gb, const float* __restrict__ Gs,
                            __bf16* __restrict__ wp, __bf16* __restrict__ gp) {
    int t = blockIdx.x * 256 + threadIdx.x;
    const int NW = 3 * 8 * 8 * 8 * 64;   // 98304 W-frag slots
    if (t < NW) {
        int lane = t & 63, nt = (t >> 6) & 7, kt = (t >> 9) & 7, e = (t >> 12) & 7, st = t >> 15;
        const float* W = (st == 0) ? Wa : (st == 1) ? Wb : Ws;
        int d  = nt * 16 + (lane & 15);
        int i0 = kt * 32 + (lane >> 4) * 8;
        __bf16* o = wp + (size_t)t * 8;
#pragma unroll
        for (int j = 0; j < 8; j++)
            o[j] = (__bf16)W[(size_t)(e * 256 + i0 + j) * 128 + d];
    } else if (t < NW + 2048) {
        int t2 = t - NW;
        int lane = t2 & 63, nt = (t2 >> 6) & 3, kt = t2 >> 8;
        int g  = nt * 16 + (lane & 15);
        int k0 = kt * 32 + (lane >> 4) * 8;
        __bf16* o = gp + (size_t)t2 * 8;
#pragma unroll
        for (int j = 0; j < 8; j++) {
            int k = k0 + j;
            float v = 0.f;
            if (g < 16)      v = Ga[g * 256 + k];
            else if (g < 32) v = Gb[(g - 16) * 256 + k];
            else if (g < 56) v = Gs[(g - 32) * 256 + k];
            o[j] = (__bf16)v;
        }
    }
}

// Load A fragments (2 row-tiles x 8 k-tiles) for one x stream, fp32->bf16.
__device__ __forceinline__ void load_afr(const float* __restrict__ x, int r0,
                                         int l16, int quad, bfv8 afr[2][8]) {
#pragma unroll
    for (int mt = 0; mt < 2; mt++) {
        const float* xr = x + (size_t)(r0 + mt * 16 + l16) * INDIM;
#pragma unroll
        for (int kt = 0; kt < 8; kt++) {
            f32x4 lo = *(const f32x4*)(xr + kt * 32 + quad * 8);
            f32x4 hi = *(const f32x4*)(xr + kt * 32 + quad * 8 + 4);
            bfv8 a;
            a[0] = (__bf16)lo[0]; a[1] = (__bf16)lo[1]; a[2] = (__bf16)lo[2]; a[3] = (__bf16)lo[3];
            a[4] = (__bf16)hi[0]; a[5] = (__bf16)hi[1]; a[6] = (__bf16)hi[2]; a[7] = (__bf16)hi[3];
            afr[mt][kt] = a;
        }
    }
}

// ---------------------------------------------------------------------------
// Main fused kernel. Grid 512 blocks (2/CU) x 256 threads (4 waves).
// Block owns 32 batch rows (mt=2). Wave w owns output cols [32w, 32w+32).
// Register discipline (the R2 lesson — arch side of a 128/128 split RF):
//   afr 64 + rotating B frags <=32 + temps ~25 = ~120 arch VGPRs; o/acc on
//   the accumulator side. No preloaded bf[8][2] (that was the spill source).
// ---------------------------------------------------------------------------
__launch_bounds__(256, 2)
__global__ void ple_kernel(const float* __restrict__ xa, const float* __restrict__ xb,
                           const float* __restrict__ xs,
                           const float* __restrict__ ba, const float* __restrict__ bb,
                           const float* __restrict__ bs,
                           const __bf16* __restrict__ wp, const __bf16* __restrict__ gp,
                           float* __restrict__ out) {
    __shared__ float lgt[ROWS * 64];   // logits [row][gate]
    __shared__ float wT[64 * ROWS];    // softmax weights transposed [gate][row]

    const int tid  = threadIdx.x;
    const int w    = tid >> 6;       // wave id 0..3
    const int lane = tid & 63;
    const int quad = lane >> 4;      // 0..3
    const int l16  = lane & 15;
    const int r0   = blockIdx.x * ROWS;

    bfv8 afr[2][8];                  // A frags: 2 row-tiles x 8 k-tiles (64 VGPRs)

    // ---------------- Phase 1: gate logits via MFMA; wave w -> gate n-tile w ----
    {
        const float* x = (w == 0) ? xa : (w == 1) ? xb : xs;  // wave-uniform branch
        load_afr(x, r0, l16, quad, afr);
        f32x4 acc[2];
#pragma unroll
        for (int mt = 0; mt < 2; mt++) { f32x4 z = {0.f, 0.f, 0.f, 0.f}; acc[mt] = z; }
#pragma unroll
        for (int kt = 0; kt < 8; kt++) {
            bfv8 g = *(const bfv8*)(gp + ((size_t)(kt * 4 + w) * 64 + lane) * 8);
#pragma unroll
            for (int mt = 0; mt < 2; mt++)
                acc[mt] = __builtin_amdgcn_mfma_f32_16x16x32_bf16(afr[mt][kt], g, acc[mt], 0, 0, 0);
        }
        // gate cols 56..63 are zero-padded in gp; their logits are ignored below
#pragma unroll
        for (int mt = 0; mt < 2; mt++)
#pragma unroll
            for (int r = 0; r < 4; r++)
                lgt[(mt * 16 + quad * 4 + r) * 64 + w * 16 + l16] = acc[mt][r];
    }
    __syncthreads();

    // ---------------- softmax per row, 3 gate groups; store transposed ----------
    if (tid < ROWS) {
        const float* L = lgt + tid * 64;
#pragma unroll
        for (int gi = 0; gi < 3; gi++) {
            const int base = (gi == 0) ? 0 : (gi == 1 ? 16 : 32);
            const int cnt  = (gi == 2) ? 24 : 16;
            float m = -1e30f;
            for (int k = 0; k < cnt; k++) m = fmaxf(m, L[base + k]);
            float s = 0.f;
            for (int k = 0; k < cnt; k++) s += __expf(L[base + k] - m);
            float inv = 1.f / s;
            for (int k = 0; k < cnt; k++) wT[(base + k) * ROWS + tid] = __expf(L[base + k] - m) * inv;
        }
    }
    __syncthreads();

    // ---------------- Phase 2: experts + gated accumulation ----------------
    float o[3][2][2][4];             // [out][mt][ntl][reg] = 48 regs (acc side)
#pragma unroll
    for (int oi = 0; oi < 3; oi++)
#pragma unroll
        for (int mt = 0; mt < 2; mt++)
#pragma unroll
            for (int ntl = 0; ntl < 2; ntl++)
#pragma unroll
                for (int r = 0; r < 4; r++) o[oi][mt][ntl][r] = 0.f;

// fold expert tile (acc, already biased) into output oi with gate column gbase+e
#define FOLD(oi, gbase)                                                            \
    {                                                                              \
        _Pragma("unroll")                                                          \
        for (int mt = 0; mt < 2; mt++) {                                           \
            f32x4 wv = *(const f32x4*)(wT + (gbase + e) * ROWS + mt * 16 + quad * 4); \
            _Pragma("unroll")                                                      \
            for (int ntl = 0; ntl < 2; ntl++)                                      \
                _Pragma("unroll")                                                  \
                for (int r = 0; r < 4; r++)                                        \
                    o[oi][mt][ntl][r] += wv[r] * acc[mt][ntl][r];                  \
        }                                                                          \
    }

#pragma unroll
    for (int st = 0; st < 3; st++) {
        const float* x    = (st == 0) ? xa : (st == 1) ? xb : xs;
        const float* bias = (st == 0) ? ba : (st == 1) ? bb : bs;
        load_afr(x, r0, l16, quad, afr);

#pragma unroll 1
        for (int e = 0; e < NEXP; e++) {
            // per-(st,e) fragment base; frag(kt,ntl) at wpe + kt*4096 + ntl*512
            const __bf16* wpe = wp + (size_t)(st * 8 + e) * 32768
                               + (size_t)(2 * w) * 512 + (size_t)lane * 8;

            f32x4 acc[2][2];
#pragma unroll
            for (int mt = 0; mt < 2; mt++)
#pragma unroll
                for (int ntl = 0; ntl < 2; ntl++) { f32x4 z = {0.f, 0.f, 0.f, 0.f}; acc[mt][ntl] = z; }

            // rotating 2-fragment prefetch: only cur+next B frags live (<=32 regs)
            bfv8 c0 = *(const bfv8*)(wpe);
            bfv8 c1 = *(const bfv8*)(wpe + 512);
#pragma unroll
            for (int kt = 0; kt < 8; kt++) {
                bfv8 n0, n1;
                if (kt < 7) {
                    n0 = *(const bfv8*)(wpe + (kt + 1) * 4096);
                    n1 = *(const bfv8*)(wpe + (kt + 1) * 4096 + 512);
                }
                acc[0][0] = __builtin_amdgcn_mfma_f32_16x16x32_bf16(afr[0][kt], c0, acc[0][0], 0, 0, 0);
                acc[1][0] = __builtin_amdgcn_mfma_f32_16x16x32_bf16(afr[1][kt], c0, acc[1][0], 0, 0, 0);
                acc[0][1] = __builtin_amdgcn_mfma_f32_16x16x32_bf16(afr[0][kt], c1, acc[0][1], 0, 0, 0);
                acc[1][1] = __builtin_amdgcn_mfma_f32_16x16x32_bf16(afr[1][kt], c1, acc[1][1], 0, 0, 0);
                if (kt < 7) { c0 = n0; c1 = n1; }
            }

            // bias (per output column)
            float b0 = bias[e * 128 + w * 32 + l16];
            float b1 = bias[e * 128 + w * 32 + 16 + l16];
#pragma unroll
            for (int mt = 0; mt < 2; mt++)
#pragma unroll
                for (int r = 0; r < 4; r++) { acc[mt][0][r] += b0; acc[mt][1][r] += b1; }

            // gated fold. Gate table columns: a:0-15, b:16-31, s:32-55.
            // out_a = cat(ea,es): ea->g=e,   es->g=8+e
            // out_b = cat(eb,es): eb->g=16+e, es->g=24+e
            // out_s = cat(ea,eb,es): ea->32+e, eb->40+e, es->48+e
            if (st == 0)      { FOLD(0, 0);  FOLD(2, 32); }
            else if (st == 1) { FOLD(1, 16); FOLD(2, 40); }
            else              { FOLD(0, 8);  FOLD(1, 24); FOLD(2, 48); }
        }
    }
#undef FOLD

    // ---------------- epilogue: store 3 outputs ----------------
#pragma unroll
    for (int oi = 0; oi < 3; oi++) {
        float* ob = out + (size_t)oi * BATCH * DDIM;
#pragma unroll
        for (int mt = 0; mt < 2; mt++)
#pragma unroll
            for (int r = 0; r < 4; r++) {
                int row = r0 + mt * 16 + quad * 4 + r;
#pragma unroll
                for (int ntl = 0; ntl < 2; ntl++)
                    ob[(size_t)row * DDIM + w * 32 + ntl * 16 + l16] = o[oi][mt][ntl][r];
            }
    }
}

extern "C" void kernel_launch(void* const* d_in, const int* in_sizes, int n_in,
                              void* d_out, int out_size, void* d_ws, size_t ws_size,
                              hipStream_t stream) {
    const float* xa = (const float*)d_in[0];
    const float* xb = (const float*)d_in[1];
    const float* xs = (const float*)d_in[2];
    const float* Wa = (const float*)d_in[3];
    const float* ba = (const float*)d_in[4];
    const float* Wb = (const float*)d_in[5];
    const float* bb = (const float*)d_in[6];
    const float* Ws = (const float*)d_in[7];
    const float* bs = (const float*)d_in[8];
    const float* Ga = (const float*)d_in[9];
    const float* Gb = (const float*)d_in[10];
    const float* Gs = (const float*)d_in[11];

    __bf16* wp = (__bf16*)d_ws;            // 786432 bf16 = 1.5 MB packed expert weights
    __bf16* gp = wp + 3 * 8 * 8 * 8 * 64 * 8;  // 16384 bf16 packed gate matrix

    prep_kernel<<<392, 256, 0, stream>>>(Wa, Wb, Ws, Ga, Gb, Gs, wp, gp);
    ple_kernel<<<BATCH / ROWS, 256, 0, stream>>>(xa, xb, xs, ba, bb, bs, wp, gp, (float*)d_out);
}

// Round 4
// 166.592 us; speedup vs baseline: 1.6424x; 1.0481x over previous
//
#include <hip/hip_runtime.h>
#include <stdint.h>

// Problem constants
#define BATCH 16384
#define INDIM 256
#define DDIM  128
#define NEXP  8
#define ROWS  32          // batch rows per block (mt=2 row-tiles of 16)

typedef __bf16 bfv8  __attribute__((ext_vector_type(8)));   // MFMA A/B frag: 8 bf16 = 4 VGPRs
typedef float  f32x4 __attribute__((ext_vector_type(4)));   // MFMA C/D frag

// ---------------------------------------------------------------------------
// Prep kernel: repack Wa/Wb/Ws (fp32 [8,256,128]) and Gcat (Ga16|Gb16|Gs24 pad
// to 64 rows) into bf16 MFMA B-fragment layout so the main kernel's B loads
// are contiguous 1KB-per-wave dwordx4.
//   W frag slot t = (((st*8+e)*8+kt)*8+nt)*64+lane ; elem j = W[i][d] with
//     i = kt*32 + (lane>>4)*8 + j,  d = nt*16 + (lane&15)
//   Flattened: for g = st*64+e*8+kt, frag(nt) lives at g*4096 + nt*512 elems.
// ---------------------------------------------------------------------------
__global__ void prep_kernel(const float* __restrict__ Wa, const float* __restrict__ Wb,
                            const float* __restrict__ Ws, const float* __restrict__ Ga,
                            const float* __restrict__ Gb, const float* __restrict__ Gs,
                            __bf16* __restrict__ wp, __bf16* __restrict__ gp) {
    int t = blockIdx.x * 256 + threadIdx.x;
    const int NW = 3 * 8 * 8 * 8 * 64;   // 98304 W-frag slots
    if (t < NW) {
        int lane = t & 63, nt = (t >> 6) & 7, kt = (t >> 9) & 7, e = (t >> 12) & 7, st = t >> 15;
        const float* W = (st == 0) ? Wa : (st == 1) ? Wb : Ws;
        int d  = nt * 16 + (lane & 15);
        int i0 = kt * 32 + (lane >> 4) * 8;
        __bf16* o = wp + (size_t)t * 8;
#pragma unroll
        for (int j = 0; j < 8; j++)
            o[j] = (__bf16)W[(size_t)(e * 256 + i0 + j) * 128 + d];
    } else if (t < NW + 2048) {
        int t2 = t - NW;
        int lane = t2 & 63, nt = (t2 >> 6) & 3, kt = t2 >> 8;
        int g  = nt * 16 + (lane & 15);
        int k0 = kt * 32 + (lane >> 4) * 8;
        __bf16* o = gp + (size_t)t2 * 8;
#pragma unroll
        for (int j = 0; j < 8; j++) {
            int k = k0 + j;
            float v = 0.f;
            if (g < 16)      v = Ga[g * 256 + k];
            else if (g < 32) v = Gb[(g - 16) * 256 + k];
            else if (g < 56) v = Gs[(g - 32) * 256 + k];
            o[j] = (__bf16)v;
        }
    }
}

// Load A fragments (2 row-tiles x 8 k-tiles) for one x stream, fp32->bf16.
__device__ __forceinline__ void load_afr(const float* __restrict__ x, int r0,
                                         int l16, int quad, bfv8 afr[2][8]) {
#pragma unroll
    for (int mt = 0; mt < 2; mt++) {
        const float* xr = x + (size_t)(r0 + mt * 16 + l16) * INDIM;
#pragma unroll
        for (int kt = 0; kt < 8; kt++) {
            f32x4 lo = *(const f32x4*)(xr + kt * 32 + quad * 8);
            f32x4 hi = *(const f32x4*)(xr + kt * 32 + quad * 8 + 4);
            bfv8 a;
            a[0] = (__bf16)lo[0]; a[1] = (__bf16)lo[1]; a[2] = (__bf16)lo[2]; a[3] = (__bf16)lo[3];
            a[4] = (__bf16)hi[0]; a[5] = (__bf16)hi[1]; a[6] = (__bf16)hi[2]; a[7] = (__bf16)hi[3];
            afr[mt][kt] = a;
        }
    }
}

// ---------------------------------------------------------------------------
// Main fused kernel. Grid 512 blocks (2/CU) x 256 threads (4 waves).
// Block owns 32 batch rows. Wave w owns output cols [32w, 32w+32).
// R4: continuous deep software pipeline over flattened g = st*64 + e*8 + kt.
// 4-slot circular B-fragment buffer, prefetch distance 4 steps => 8
// outstanding 1KB loads per wave at steady state; compiler emits fine-grained
// vmcnt waits (never a drain). Register audit: afr 64 + slots 32 + o 48 +
// acc 16 + temps ~25 = ~185 <= 256 cap at (256,2). No spills.
// ---------------------------------------------------------------------------
__launch_bounds__(256, 2)
__global__ void ple_kernel(const float* __restrict__ xa, const float* __restrict__ xb,
                           const float* __restrict__ xs,
                           const float* __restrict__ ba, const float* __restrict__ bb,
                           const float* __restrict__ bs,
                           const __bf16* __restrict__ wp, const __bf16* __restrict__ gp,
                           float* __restrict__ out) {
    __shared__ float lgt[ROWS * 64];   // logits [row][gate]
    __shared__ float wT[64 * ROWS];    // softmax weights transposed [gate][row]

    const int tid  = threadIdx.x;
    const int w    = tid >> 6;       // wave id 0..3
    const int lane = tid & 63;
    const int quad = lane >> 4;      // 0..3
    const int l16  = lane & 15;
    const int r0   = blockIdx.x * ROWS;

    bfv8 afr[2][8];                  // A frags: 2 row-tiles x 8 k-tiles (64 VGPRs)

    // ---------------- Phase 1: gate logits via MFMA; wave w -> gate n-tile w ----
    {
        const float* x = (w == 0) ? xa : (w == 1) ? xb : xs;  // wave-uniform branch
        load_afr(x, r0, l16, quad, afr);
        f32x4 acc[2];
#pragma unroll
        for (int mt = 0; mt < 2; mt++) { f32x4 z = {0.f, 0.f, 0.f, 0.f}; acc[mt] = z; }
#pragma unroll
        for (int kt = 0; kt < 8; kt++) {
            bfv8 g = *(const bfv8*)(gp + ((size_t)(kt * 4 + w) * 64 + lane) * 8);
#pragma unroll
            for (int mt = 0; mt < 2; mt++)
                acc[mt] = __builtin_amdgcn_mfma_f32_16x16x32_bf16(afr[mt][kt], g, acc[mt], 0, 0, 0);
        }
#pragma unroll
        for (int mt = 0; mt < 2; mt++)
#pragma unroll
            for (int r = 0; r < 4; r++)
                lgt[(mt * 16 + quad * 4 + r) * 64 + w * 16 + l16] = acc[mt][r];
    }
    __syncthreads();

    // ---------------- softmax per row, 3 gate groups; store transposed ----------
    if (tid < ROWS) {
        const float* L = lgt + tid * 64;
#pragma unroll
        for (int gi = 0; gi < 3; gi++) {
            const int base = (gi == 0) ? 0 : (gi == 1 ? 16 : 32);
            const int cnt  = (gi == 2) ? 24 : 16;
            float m = -1e30f;
            for (int k = 0; k < cnt; k++) m = fmaxf(m, L[base + k]);
            float s = 0.f;
            for (int k = 0; k < cnt; k++) s += __expf(L[base + k] - m);
            float inv = 1.f / s;
            for (int k = 0; k < cnt; k++) wT[(base + k) * ROWS + tid] = __expf(L[base + k] - m) * inv;
        }
    }
    __syncthreads();

    // ---------------- Phase 2: experts + gated accumulation ----------------
    float o[3][2][2][4];             // [out][mt][ntl][reg]
#pragma unroll
    for (int oi = 0; oi < 3; oi++)
#pragma unroll
        for (int mt = 0; mt < 2; mt++)
#pragma unroll
            for (int ntl = 0; ntl < 2; ntl++)
#pragma unroll
                for (int r = 0; r < 4; r++) o[oi][mt][ntl][r] = 0.f;

// fold expert tile (acc, already biased) into output oi with gate column gbase+e
#define FOLD(oi, gbase)                                                            \
    {                                                                              \
        _Pragma("unroll")                                                          \
        for (int mt = 0; mt < 2; mt++) {                                           \
            f32x4 wv = *(const f32x4*)(wT + (gbase + eb) * ROWS + mt * 16 + quad * 4); \
            _Pragma("unroll")                                                      \
            for (int ntl = 0; ntl < 2; ntl++)                                      \
                _Pragma("unroll")                                                  \
                for (int r = 0; r < 4; r++)                                        \
                    o[oi][mt][ntl][r] += wv[r] * acc[mt][ntl][r];                  \
        }                                                                          \
    }

    // Per-wave column base inside each 4096-elem fragment group.
    const __bf16* colb = wp + (size_t)(2 * w) * 512 + (size_t)lane * 8;

    bfv8 cb[4][2];                   // circular B buffer: 4 steps x 2 ntl (32 VGPRs)
    // Prologue: prime pipeline with steps g = 0..3 (st0, e0, kt0..3)
#pragma unroll
    for (int i = 0; i < 4; i++) {
        cb[i][0] = *(const bfv8*)(colb + (size_t)i * 4096);
        cb[i][1] = *(const bfv8*)(colb + (size_t)i * 4096 + 512);
    }

#pragma unroll
    for (int st = 0; st < 3; st++) {
        const float* x    = (st == 0) ? xa : (st == 1) ? xb : xs;
        const float* bias = (st == 0) ? ba : (st == 1) ? bb : bs;
        load_afr(x, r0, l16, quad, afr);

#pragma unroll 1
        for (int eb = 0; eb < NEXP; eb++) {
            // hoist bias loads: consumed after the kt loop, latency hidden
            float b0 = bias[eb * 128 + w * 32 + l16];
            float b1 = bias[eb * 128 + w * 32 + 16 + l16];

            f32x4 acc[2][2];
#pragma unroll
            for (int mt = 0; mt < 2; mt++)
#pragma unroll
                for (int ntl = 0; ntl < 2; ntl++) { f32x4 z = {0.f, 0.f, 0.f, 0.f}; acc[mt][ntl] = z; }

#pragma unroll
            for (int kt = 0; kt < 8; kt++) {
                const int sl = kt & 3;
                acc[0][0] = __builtin_amdgcn_mfma_f32_16x16x32_bf16(afr[0][kt], cb[sl][0], acc[0][0], 0, 0, 0);
                acc[1][0] = __builtin_amdgcn_mfma_f32_16x16x32_bf16(afr[1][kt], cb[sl][0], acc[1][0], 0, 0, 0);
                acc[0][1] = __builtin_amdgcn_mfma_f32_16x16x32_bf16(afr[0][kt], cb[sl][1], acc[0][1], 0, 0, 0);
                acc[1][1] = __builtin_amdgcn_mfma_f32_16x16x32_bf16(afr[1][kt], cb[sl][1], acc[1][1], 0, 0, 0);
                // prefetch step g+4 into the slot just consumed (WAR ok at issue)
                if (kt < 4 || st < 2 || eb < NEXP - 1) {
                    size_t gpf = (size_t)(st * 64 + eb * 8 + kt + 4) * 4096;
                    cb[sl][0] = *(const bfv8*)(colb + gpf);
                    cb[sl][1] = *(const bfv8*)(colb + gpf + 512);
                }
            }

            // bias (per output column)
#pragma unroll
            for (int mt = 0; mt < 2; mt++)
#pragma unroll
                for (int r = 0; r < 4; r++) { acc[mt][0][r] += b0; acc[mt][1][r] += b1; }

            // gated fold. Gate table columns: a:0-15, b:16-31, s:32-55.
            // out_a = cat(ea,es): ea->g=e,   es->g=8+e
            // out_b = cat(eb,es): eb->g=16+e, es->g=24+e
            // out_s = cat(ea,eb,es): ea->32+e, eb->40+e, es->48+e
            if (st == 0)      { FOLD(0, 0);  FOLD(2, 32); }
            else if (st == 1) { FOLD(1, 16); FOLD(2, 40); }
            else              { FOLD(0, 8);  FOLD(1, 24); FOLD(2, 48); }
        }
    }
#undef FOLD

    // ---------------- epilogue: store 3 outputs ----------------
#pragma unroll
    for (int oi = 0; oi < 3; oi++) {
        float* ob = out + (size_t)oi * BATCH * DDIM;
#pragma unroll
        for (int mt = 0; mt < 2; mt++)
#pragma unroll
            for (int r = 0; r < 4; r++) {
                int row = r0 + mt * 16 + quad * 4 + r;
#pragma unroll
                for (int ntl = 0; ntl < 2; ntl++)
                    ob[(size_t)row * DDIM + w * 32 + ntl * 16 + l16] = o[oi][mt][ntl][r];
            }
    }
}

extern "C" void kernel_launch(void* const* d_in, const int* in_sizes, int n_in,
                              void* d_out, int out_size, void* d_ws, size_t ws_size,
                              hipStream_t stream) {
    const float* xa = (const float*)d_in[0];
    const float* xb = (const float*)d_in[1];
    const float* xs = (const float*)d_in[2];
    const float* Wa = (const float*)d_in[3];
    const float* ba = (const float*)d_in[4];
    const float* Wb = (const float*)d_in[5];
    const float* bb = (const float*)d_in[6];
    const float* Ws = (const float*)d_in[7];
    const float* bs = (const float*)d_in[8];
    const float* Ga = (const float*)d_in[9];
    const float* Gb = (const float*)d_in[10];
    const float* Gs = (const float*)d_in[11];

    __bf16* wp = (__bf16*)d_ws;            // 786432 bf16 = 1.5 MB packed expert weights
    __bf16* gp = wp + 3 * 8 * 8 * 8 * 64 * 8;  // 16384 bf16 packed gate matrix

    prep_kernel<<<392, 256, 0, stream>>>(Wa, Wb, Ws, Ga, Gb, Gs, wp, gp);
    ple_kernel<<<BATCH / ROWS, 256, 0, stream>>>(xa, xb, xs, ba, bb, bs, wp, gp, (float*)d_out);
}